// Round 1
// baseline (303.390 us; speedup 1.0000x reference)
//
#include <hip/hip_runtime.h>
#include <math.h>

// B=16, H=12, S=1024, D=64.  BH=192, rows = B*H*S = 196608.
// ws layout (bf16): Q[196608*64] | K[196608*64] | Vt[192*64*1024] | AO[196608*64]
//   = 4 * 25,165,824 B = 100,663,296 B total.

typedef __bf16 bf16x8 __attribute__((ext_vector_type(8)));
typedef float  f32x4  __attribute__((ext_vector_type(4)));

#define MFMA(a, b, c) __builtin_amdgcn_mfma_f32_16x16x32_bf16((a), (b), (c), 0, 0, 0)

static constexpr int S = 1024;
static constexpr int D = 64;
static constexpr int LDS_PAD = 72;   // 144 B row stride: 16B-aligned, breaks 128B bank aliasing
static constexpr size_t NE = 196608ull * 64ull;  // elements per ws tensor

// ---------------------------------------------------------------------------
// Kernel 1: Q/K/V projection.  Block = 256 thr (4 waves) handles 64 rows.
// q = (x@Wq^T + bq) * 0.125 (fold 1/sqrt(D) into Q), k = x@Wk^T + bk,
// v = x@Wv^T + bv stored TRANSPOSED per (b,h): Vt[bh][d][s].
// ---------------------------------------------------------------------------
__global__ __launch_bounds__(256) void proj_qkv(
    const float* __restrict__ x,
    const float* __restrict__ Wq, const float* __restrict__ bq,
    const float* __restrict__ Wk, const float* __restrict__ bk,
    const float* __restrict__ Wv, const float* __restrict__ bv,
    __bf16* __restrict__ gq, __bf16* __restrict__ gk, __bf16* __restrict__ gvt)
{
    __shared__ __align__(16) __bf16 lx[64][LDS_PAD];
    __shared__ __align__(16) __bf16 lw[3][64][LDS_PAD];
    __shared__ float lb[3][64];

    const int tid = threadIdx.x;
    const int row_base = blockIdx.x * 64;

    // stage x tile (64x64 fp32 -> bf16)
    #pragma unroll
    for (int i = tid * 4; i < 4096; i += 1024) {
        float4 v = *(const float4*)(x + (size_t)row_base * 64 + i);
        int r = i >> 6, c = i & 63;
        lx[r][c]     = (__bf16)v.x;
        lx[r][c + 1] = (__bf16)v.y;
        lx[r][c + 2] = (__bf16)v.z;
        lx[r][c + 3] = (__bf16)v.w;
    }
    // stage Wq, Wk, Wv (row-major [e][d]) -> bf16
    const float* Ws[3] = {Wq, Wk, Wv};
    #pragma unroll
    for (int mtx = 0; mtx < 3; mtx++) {
        for (int i = tid * 4; i < 4096; i += 1024) {
            float4 v = *(const float4*)(Ws[mtx] + i);
            int r = i >> 6, c = i & 63;
            lw[mtx][r][c]     = (__bf16)v.x;
            lw[mtx][r][c + 1] = (__bf16)v.y;
            lw[mtx][r][c + 2] = (__bf16)v.z;
            lw[mtx][r][c + 3] = (__bf16)v.w;
        }
    }
    if (tid < 64) { lb[0][tid] = bq[tid]; lb[1][tid] = bk[tid]; lb[2][tid] = bv[tid]; }
    __syncthreads();

    const int w = tid >> 6, lane = tid & 63, m = lane & 15, quad = lane >> 4;
    const int bh = row_base >> 10;
    const int s_base = row_base & 1023;

    // A-frags: x rows (w*16 + m), k = quad*8 + j  (two 32-wide chunks)
    bf16x8 a0 = *(const bf16x8*)&lx[w * 16 + m][quad * 8];
    bf16x8 a1 = *(const bf16x8*)&lx[w * 16 + m][32 + quad * 8];

    #pragma unroll
    for (int mtx = 0; mtx < 3; mtx++) {
        #pragma unroll
        for (int n0 = 0; n0 < 64; n0 += 16) {
            bf16x8 b0 = *(const bf16x8*)&lw[mtx][n0 + m][quad * 8];
            bf16x8 b1 = *(const bf16x8*)&lw[mtx][n0 + m][32 + quad * 8];
            f32x4 acc = {0.f, 0.f, 0.f, 0.f};
            acc = MFMA(a0, b0, acc);
            acc = MFMA(a1, b1, acc);
            const int col = n0 + m;
            const float bias = lb[mtx][col];
            if (mtx == 0) {
                #pragma unroll
                for (int r = 0; r < 4; r++) {
                    int sl = w * 16 + quad * 4 + r;
                    gq[((size_t)row_base + sl) * 64 + col] = (__bf16)((acc[r] + bias) * 0.125f);
                }
            } else if (mtx == 1) {
                #pragma unroll
                for (int r = 0; r < 4; r++) {
                    int sl = w * 16 + quad * 4 + r;
                    gk[((size_t)row_base + sl) * 64 + col] = (__bf16)(acc[r] + bias);
                }
            } else {
                // Vt[bh][col][s_base + w*16 + quad*4 + r] : 4 consecutive s -> one 8B store
                union { __bf16 h[4]; unsigned long long u; } pk;
                #pragma unroll
                for (int r = 0; r < 4; r++) pk.h[r] = (__bf16)(acc[r] + bias);
                *(unsigned long long*)(gvt + ((size_t)bh * 64 + col) * 1024 + s_base + w * 16 + quad * 4) = pk.u;
            }
        }
    }
}

// ---------------------------------------------------------------------------
// Kernel 2: flash attention.  Block = 256 thr (4 waves) handles (bh, 64 q rows);
// each wave owns 16 q rows.  Loop over 16 key-blocks of 64 keys.
// ---------------------------------------------------------------------------
__global__ __launch_bounds__(256) void attn(
    const __bf16* __restrict__ gq, const __bf16* __restrict__ gk,
    const __bf16* __restrict__ gvt, __bf16* __restrict__ gao)
{
    __shared__ __align__(16) __bf16 lk[64][LDS_PAD];       // K tile [key][d]
    __shared__ __align__(16) __bf16 lv[64][LDS_PAD];       // Vt tile [d][key]
    __shared__ __align__(16) __bf16 lp[4][16][LDS_PAD];    // per-wave P roundtrip

    const int tid = threadIdx.x;
    const int w = tid >> 6, lane = tid & 63, m = lane & 15, quad = lane >> 4;
    const int bh = blockIdx.y;
    const int q_base = blockIdx.x * 64;

    // Q A-frags: rows q_base + w*16 + m, direct 16B global loads (Q pre-scaled)
    const __bf16* qrow = gq + ((size_t)bh * S + q_base + w * 16 + m) * 64;
    bf16x8 qa0 = *(const bf16x8*)(qrow + quad * 8);
    bf16x8 qa1 = *(const bf16x8*)(qrow + 32 + quad * 8);

    f32x4 o[4];
    float m_run[4], l_run[4];
    #pragma unroll
    for (int n = 0; n < 4; n++) o[n] = {0.f, 0.f, 0.f, 0.f};
    #pragma unroll
    for (int r = 0; r < 4; r++) { m_run[r] = -INFINITY; l_run[r] = 0.f; }

    for (int kb = 0; kb < 16; kb++) {
        // stage K tile and Vt tile (each 64x64 bf16, 16B vector copies)
        #pragma unroll
        for (int i = tid; i < 512; i += 256) {
            int r = i >> 3, c = (i & 7) * 8;
            *(uint4*)&lk[r][c] = *(const uint4*)(gk + ((size_t)bh * S + kb * 64 + r) * 64 + c);
            *(uint4*)&lv[r][c] = *(const uint4*)(gvt + ((size_t)bh * 64 + r) * 1024 + kb * 64 + c);
        }
        __syncthreads();

        // scores: 4 sub-tiles of 16 keys, 2 MFMAs each (d = 0..31, 32..63)
        f32x4 s[4];
        #pragma unroll
        for (int t = 0; t < 4; t++) {
            bf16x8 kb0 = *(const bf16x8*)&lk[t * 16 + m][quad * 8];
            bf16x8 kb1 = *(const bf16x8*)&lk[t * 16 + m][32 + quad * 8];
            f32x4 acc = {0.f, 0.f, 0.f, 0.f};
            acc = MFMA(qa0, kb0, acc);
            acc = MFMA(qa1, kb1, acc);
            s[t] = acc;
        }

        // online softmax (rows = quad*4 + r, replicated across the 16 lanes of a quad)
        float rm[4];
        #pragma unroll
        for (int r = 0; r < 4; r++)
            rm[r] = fmaxf(fmaxf(s[0][r], s[1][r]), fmaxf(s[2][r], s[3][r]));
        #pragma unroll
        for (int off = 1; off < 16; off <<= 1)
            #pragma unroll
            for (int r = 0; r < 4; r++) rm[r] = fmaxf(rm[r], __shfl_xor(rm[r], off));

        float al[4], rs[4];
        #pragma unroll
        for (int r = 0; r < 4; r++) {
            float mn = fmaxf(m_run[r], rm[r]);
            al[r] = __expf(m_run[r] - mn);
            m_run[r] = mn;
            rs[r] = 0.f;
        }
        #pragma unroll
        for (int t = 0; t < 4; t++)
            #pragma unroll
            for (int r = 0; r < 4; r++) {
                float p = __expf(s[t][r] - m_run[r]);
                s[t][r] = p;
                rs[r] += p;
            }
        #pragma unroll
        for (int off = 1; off < 16; off <<= 1)
            #pragma unroll
            for (int r = 0; r < 4; r++) rs[r] += __shfl_xor(rs[r], off);
        #pragma unroll
        for (int r = 0; r < 4; r++) l_run[r] = l_run[r] * al[r] + rs[r];
        #pragma unroll
        for (int n = 0; n < 4; n++)
            #pragma unroll
            for (int r = 0; r < 4; r++) o[n][r] *= al[r];

        // P: C-layout -> LDS -> A-layout (per-wave buffer, intra-wave ordering)
        #pragma unroll
        for (int t = 0; t < 4; t++)
            #pragma unroll
            for (int r = 0; r < 4; r++)
                lp[w][quad * 4 + r][t * 16 + m] = (__bf16)s[t][r];

        bf16x8 pa0 = *(const bf16x8*)&lp[w][m][quad * 8];
        bf16x8 pa1 = *(const bf16x8*)&lp[w][m][32 + quad * 8];

        // PV: O[q][d] += P[q][key] * V[key][d]; Vt gives contiguous B-frags
        #pragma unroll
        for (int n = 0; n < 4; n++) {
            bf16x8 vb0 = *(const bf16x8*)&lv[n * 16 + m][quad * 8];
            bf16x8 vb1 = *(const bf16x8*)&lv[n * 16 + m][32 + quad * 8];
            o[n] = MFMA(pa0, vb0, o[n]);
            o[n] = MFMA(pa1, vb1, o[n]);
        }
        __syncthreads();
    }

    // epilogue: O /= l, store bf16 [bh][s][d]
    float inv[4];
    #pragma unroll
    for (int r = 0; r < 4; r++) inv[r] = 1.f / l_run[r];
    #pragma unroll
    for (int n = 0; n < 4; n++)
        #pragma unroll
        for (int r = 0; r < 4; r++) {
            int sl = w * 16 + quad * 4 + r;
            gao[((size_t)bh * S + q_base + sl) * 64 + n * 16 + m] = (__bf16)(o[n][r] * inv[r]);
        }
}

// ---------------------------------------------------------------------------
// Kernel 3: output projection.  out = ao @ Wo^T + bo  (fp32 out)
// ---------------------------------------------------------------------------
__global__ __launch_bounds__(256) void out_proj(
    const __bf16* __restrict__ gao, const float* __restrict__ Wo,
    const float* __restrict__ bo, float* __restrict__ out)
{
    __shared__ __align__(16) __bf16 lx[64][LDS_PAD];
    __shared__ __align__(16) __bf16 lw[64][LDS_PAD];
    __shared__ float lb[64];

    const int tid = threadIdx.x;
    const int row_base = blockIdx.x * 64;

    #pragma unroll
    for (int i = tid; i < 512; i += 256) {
        int r = i >> 3, c = (i & 7) * 8;
        *(uint4*)&lx[r][c] = *(const uint4*)(gao + (size_t)row_base * 64 + r * 64 + c);
    }
    #pragma unroll
    for (int i = tid * 4; i < 4096; i += 1024) {
        float4 v = *(const float4*)(Wo + i);
        int r = i >> 6, c = i & 63;
        lw[r][c]     = (__bf16)v.x;
        lw[r][c + 1] = (__bf16)v.y;
        lw[r][c + 2] = (__bf16)v.z;
        lw[r][c + 3] = (__bf16)v.w;
    }
    if (tid < 64) lb[tid] = bo[tid];
    __syncthreads();

    const int w = tid >> 6, lane = tid & 63, m = lane & 15, quad = lane >> 4;
    bf16x8 a0 = *(const bf16x8*)&lx[w * 16 + m][quad * 8];
    bf16x8 a1 = *(const bf16x8*)&lx[w * 16 + m][32 + quad * 8];

    #pragma unroll
    for (int n0 = 0; n0 < 64; n0 += 16) {
        bf16x8 b0 = *(const bf16x8*)&lw[n0 + m][quad * 8];
        bf16x8 b1 = *(const bf16x8*)&lw[n0 + m][32 + quad * 8];
        f32x4 acc = {0.f, 0.f, 0.f, 0.f};
        acc = MFMA(a0, b0, acc);
        acc = MFMA(a1, b1, acc);
        const int col = n0 + m;
        const float bias = lb[col];
        #pragma unroll
        for (int r = 0; r < 4; r++) {
            int sl = w * 16 + quad * 4 + r;
            out[((size_t)row_base + sl) * 64 + col] = acc[r] + bias;
        }
    }
}

// ---------------------------------------------------------------------------
extern "C" void kernel_launch(void* const* d_in, const int* in_sizes, int n_in,
                              void* d_out, int out_size, void* d_ws, size_t ws_size,
                              hipStream_t stream) {
    const float* x  = (const float*)d_in[0];
    const float* Wq = (const float*)d_in[1];
    const float* bq = (const float*)d_in[2];
    const float* Wk = (const float*)d_in[3];
    const float* bk = (const float*)d_in[4];
    const float* Wv = (const float*)d_in[5];
    const float* bv = (const float*)d_in[6];
    const float* Wo = (const float*)d_in[7];
    const float* bo = (const float*)d_in[8];
    float* out = (float*)d_out;

    __bf16* gq  = (__bf16*)d_ws;
    __bf16* gk  = gq + NE;
    __bf16* gvt = gk + NE;
    __bf16* gao = gvt + NE;

    proj_qkv<<<3072, 256, 0, stream>>>(x, Wq, bq, Wk, bk, Wv, bv, gq, gk, gvt);
    attn<<<dim3(16, 192), 256, 0, stream>>>(gq, gk, gvt, gao);
    out_proj<<<3072, 256, 0, stream>>>(gao, Wo, bo, out);
}

// Round 2
// 242.345 us; speedup vs baseline: 1.2519x; 1.2519x over previous
//
#include <hip/hip_runtime.h>
#include <math.h>

// B=16, H=12, S=1024, D=64.  BH=192, rows = B*H*S = 196608.
// ws layout (bf16): Q[196608*64] | K[196608*64] | Vt[192*64*1024] | AO[196608*64]

typedef __bf16 bf16x8 __attribute__((ext_vector_type(8)));
typedef float  f32x4  __attribute__((ext_vector_type(4)));

#define MFMA(a, b, c) __builtin_amdgcn_mfma_f32_16x16x32_bf16((a), (b), (c), 0, 0, 0)

static constexpr int S = 1024;
static constexpr int LDS_PAD = 72;   // 144 B row stride: 16B-aligned, breaks 128B bank aliasing
static constexpr size_t NE = 196608ull * 64ull;

__device__ inline unsigned long long pack4bf(float a, float b, float c, float d) {
    union { __bf16 h[4]; unsigned long long u; } pk;
    pk.h[0] = (__bf16)a; pk.h[1] = (__bf16)b; pk.h[2] = (__bf16)c; pk.h[3] = (__bf16)d;
    return pk.u;
}

// ---------------------------------------------------------------------------
// Kernel 1: Q/K/V projection.  Block = 256 thr (4 waves), 128 rows/block.
// Q,K computed transposed (A=W) -> packed 8B stores; V computed direct (A=x)
// so Vt[bh][d][s] gets packed 8B stores along s.
// Q pre-scaled by 1/sqrt(D)=0.125.
// ---------------------------------------------------------------------------
__global__ __launch_bounds__(256) void proj_qkv(
    const float* __restrict__ x,
    const float* __restrict__ Wq, const float* __restrict__ bq,
    const float* __restrict__ Wk, const float* __restrict__ bk,
    const float* __restrict__ Wv, const float* __restrict__ bv,
    __bf16* __restrict__ gq, __bf16* __restrict__ gk, __bf16* __restrict__ gvt)
{
    __shared__ __align__(16) __bf16 lx[128][LDS_PAD];
    __shared__ __align__(16) __bf16 lw[3][64][LDS_PAD];
    __shared__ float lb[3][64];

    const int tid = threadIdx.x;
    const int row_base = blockIdx.x * 128;

    // stage x tile (128x64 fp32 -> bf16, packed 8B LDS writes)
    #pragma unroll
    for (int i = tid * 4; i < 8192; i += 1024) {
        float4 v = *(const float4*)(x + (size_t)row_base * 64 + i);
        int r = i >> 6, c = i & 63;
        *(unsigned long long*)&lx[r][c] = pack4bf(v.x, v.y, v.z, v.w);
    }
    const float* Ws[3] = {Wq, Wk, Wv};
    #pragma unroll
    for (int mtx = 0; mtx < 3; mtx++) {
        #pragma unroll
        for (int i = tid * 4; i < 4096; i += 1024) {
            float4 v = *(const float4*)(Ws[mtx] + i);
            int r = i >> 6, c = i & 63;
            *(unsigned long long*)&lw[mtx][r][c] = pack4bf(v.x, v.y, v.z, v.w);
        }
    }
    if (tid < 64) { lb[0][tid] = bq[tid]; lb[1][tid] = bk[tid]; lb[2][tid] = bv[tid]; }
    __syncthreads();

    const int w = tid >> 6, lane = tid & 63, m = lane & 15, quad = lane >> 4;
    const int bh = row_base >> 10;
    const int s_base = row_base & 1023;

    // x frags for two 16-row sets (serve as A- or B-operand: same register data)
    bf16x8 xf[2][2];
    #pragma unroll
    for (int g = 0; g < 2; g++) {
        xf[g][0] = *(const bf16x8*)&lx[w * 32 + g * 16 + m][quad * 8];
        xf[g][1] = *(const bf16x8*)&lx[w * 32 + g * 16 + m][32 + quad * 8];
    }

    #pragma unroll
    for (int mtx = 0; mtx < 3; mtx++) {
        #pragma unroll
        for (int et = 0; et < 4; et++) {
            bf16x8 wf0 = *(const bf16x8*)&lw[mtx][et * 16 + m][quad * 8];
            bf16x8 wf1 = *(const bf16x8*)&lw[mtx][et * 16 + m][32 + quad * 8];
            if (mtx < 2) {
                // C[e][s]: e = et*16 + quad*4 + r, s = row_base + w*32 + g*16 + m
                float4 bias = *(const float4*)&lb[mtx][et * 16 + quad * 4];
                #pragma unroll
                for (int g = 0; g < 2; g++) {
                    f32x4 acc = {0.f, 0.f, 0.f, 0.f};
                    acc = MFMA(wf0, xf[g][0], acc);
                    acc = MFMA(wf1, xf[g][1], acc);
                    size_t row = (size_t)row_base + w * 32 + g * 16 + m;
                    unsigned long long u;
                    if (mtx == 0)
                        u = pack4bf((acc[0] + bias.x) * 0.125f, (acc[1] + bias.y) * 0.125f,
                                    (acc[2] + bias.z) * 0.125f, (acc[3] + bias.w) * 0.125f);
                    else
                        u = pack4bf(acc[0] + bias.x, acc[1] + bias.y,
                                    acc[2] + bias.z, acc[3] + bias.w);
                    __bf16* dst = (mtx == 0 ? gq : gk);
                    *(unsigned long long*)(dst + row * 64 + et * 16 + quad * 4) = u;
                }
            } else {
                // C[s][e]: s = w*32 + g*16 + quad*4 + r, e = et*16 + m
                const int e = et * 16 + m;
                const float bias = lb[2][e];
                #pragma unroll
                for (int g = 0; g < 2; g++) {
                    f32x4 acc = {0.f, 0.f, 0.f, 0.f};
                    acc = MFMA(xf[g][0], wf0, acc);
                    acc = MFMA(xf[g][1], wf1, acc);
                    unsigned long long u = pack4bf(acc[0] + bias, acc[1] + bias,
                                                   acc[2] + bias, acc[3] + bias);
                    int sl = s_base + w * 32 + g * 16 + quad * 4;
                    *(unsigned long long*)(gvt + ((size_t)bh * 64 + e) * 1024 + sl) = u;
                }
            }
        }
    }
}

// ---------------------------------------------------------------------------
// Kernel 2: flash attention, transposed dataflow.
// Block = 256 thr (4 waves), 128 q rows/block; each wave owns 32 q rows.
// S^T = K * Q^T  => per-lane scalar softmax stats (col = q = lane&15).
// O^T = V^T * P^T accumulated in C-layout; packed stores.
// ---------------------------------------------------------------------------
__global__ __launch_bounds__(256) void attn(
    const __bf16* __restrict__ gq, const __bf16* __restrict__ gk,
    const __bf16* __restrict__ gvt, __bf16* __restrict__ gao)
{
    __shared__ __align__(16) __bf16 lk[64][LDS_PAD];        // K tile [key][d]
    __shared__ __align__(16) __bf16 lv[64][LDS_PAD];        // Vt tile [d][key]
    __shared__ __align__(16) __bf16 lpT[4][32][LDS_PAD];    // per-wave P^T roundtrip [q][key]

    const int tid = threadIdx.x;
    const int w = tid >> 6, lane = tid & 63, m = lane & 15, quad = lane >> 4;
    const int bh = blockIdx.y;
    const int q0 = blockIdx.x * 128 + w * 32;

    // Q frags (B-operand) for two 16-row sets
    bf16x8 qf[2][2];
    #pragma unroll
    for (int g = 0; g < 2; g++) {
        const __bf16* qrow = gq + ((size_t)bh * S + q0 + g * 16 + m) * 64;
        qf[g][0] = *(const bf16x8*)(qrow + quad * 8);
        qf[g][1] = *(const bf16x8*)(qrow + 32 + quad * 8);
    }

    f32x4 o[2][4];
    float m_run[2], l_run[2];
    #pragma unroll
    for (int g = 0; g < 2; g++) {
        m_run[g] = -INFINITY; l_run[g] = 0.f;
        #pragma unroll
        for (int n = 0; n < 4; n++) o[g][n] = {0.f, 0.f, 0.f, 0.f};
    }

    // staging: each thread copies 2 uint4 per tile; register prefetch 1 kb ahead
    const int sr = tid >> 3;            // 0..31
    const int sc = (tid & 7) * 8;       // element col (16B chunk)
    const __bf16* kbase = gk + (size_t)bh * S * 64;
    const __bf16* vbase = gvt + (size_t)bh * 64 * 1024;

    uint4 kreg0 = *(const uint4*)(kbase + (size_t)sr * 64 + sc);
    uint4 kreg1 = *(const uint4*)(kbase + (size_t)(sr + 32) * 64 + sc);
    uint4 vreg0 = *(const uint4*)(vbase + (size_t)sr * 1024 + sc);
    uint4 vreg1 = *(const uint4*)(vbase + (size_t)(sr + 32) * 1024 + sc);

    for (int kb = 0; kb < 16; kb++) {
        __syncthreads();   // prior iter's LDS reads complete
        *(uint4*)&lk[sr][sc]      = kreg0;
        *(uint4*)&lk[sr + 32][sc] = kreg1;
        *(uint4*)&lv[sr][sc]      = vreg0;
        *(uint4*)&lv[sr + 32][sc] = vreg1;
        if (kb < 15) {
            const int nb = (kb + 1) * 64;
            kreg0 = *(const uint4*)(kbase + (size_t)(nb + sr) * 64 + sc);
            kreg1 = *(const uint4*)(kbase + (size_t)(nb + sr + 32) * 64 + sc);
            vreg0 = *(const uint4*)(vbase + (size_t)sr * 1024 + nb + sc);
            vreg1 = *(const uint4*)(vbase + (size_t)(sr + 32) * 1024 + nb + sc);
        }
        __syncthreads();

        // scores S^T: rows = keys (tile t), cols = q
        f32x4 s[2][4];
        #pragma unroll
        for (int t = 0; t < 4; t++) {
            bf16x8 ka0 = *(const bf16x8*)&lk[t * 16 + m][quad * 8];
            bf16x8 ka1 = *(const bf16x8*)&lk[t * 16 + m][32 + quad * 8];
            #pragma unroll
            for (int g = 0; g < 2; g++) {
                f32x4 acc = {0.f, 0.f, 0.f, 0.f};
                acc = MFMA(ka0, qf[g][0], acc);
                acc = MFMA(ka1, qf[g][1], acc);
                s[g][t] = acc;
            }
        }

        // online softmax: per-lane q column; keys split 16-local x 4-quads
        #pragma unroll
        for (int g = 0; g < 2; g++) {
            float lm = -INFINITY;
            #pragma unroll
            for (int t = 0; t < 4; t++) {
                float tm = fmaxf(fmaxf(s[g][t][0], s[g][t][1]),
                                 fmaxf(s[g][t][2], s[g][t][3]));
                lm = fmaxf(lm, tm);
            }
            lm = fmaxf(lm, __shfl_xor(lm, 16));
            lm = fmaxf(lm, __shfl_xor(lm, 32));
            const float mn = fmaxf(m_run[g], lm);
            const float al = __expf(m_run[g] - mn);
            m_run[g] = mn;
            float rs = 0.f;
            #pragma unroll
            for (int t = 0; t < 4; t++) {
                #pragma unroll
                for (int r = 0; r < 4; r++) {
                    float p = __expf(s[g][t][r] - mn);
                    s[g][t][r] = p;
                    rs += p;
                }
            }
            rs += __shfl_xor(rs, 16);
            rs += __shfl_xor(rs, 32);
            l_run[g] = l_run[g] * al + rs;
            #pragma unroll
            for (int n = 0; n < 4; n++) {
                o[g][n][0] *= al; o[g][n][1] *= al;
                o[g][n][2] *= al; o[g][n][3] *= al;
            }
            // P^T -> LDS as [q][key]: lane holds keys 16t+4*quad+r for q=m
            #pragma unroll
            for (int t = 0; t < 4; t++) {
                *(unsigned long long*)&lpT[w][g * 16 + m][t * 16 + quad * 4] =
                    pack4bf(s[g][t][0], s[g][t][1], s[g][t][2], s[g][t][3]);
            }
        }

        // PV: O^T[d][q] += V^T[d][key] * P^T-as-B[key][q]
        bf16x8 pb[2][2];
        #pragma unroll
        for (int g = 0; g < 2; g++) {
            pb[g][0] = *(const bf16x8*)&lpT[w][g * 16 + m][quad * 8];
            pb[g][1] = *(const bf16x8*)&lpT[w][g * 16 + m][32 + quad * 8];
        }
        #pragma unroll
        for (int n = 0; n < 4; n++) {
            bf16x8 va0 = *(const bf16x8*)&lv[n * 16 + m][quad * 8];
            bf16x8 va1 = *(const bf16x8*)&lv[n * 16 + m][32 + quad * 8];
            #pragma unroll
            for (int g = 0; g < 2; g++) {
                o[g][n] = MFMA(va0, pb[g][0], o[g][n]);
                o[g][n] = MFMA(va1, pb[g][1], o[g][n]);
            }
        }
    }

    // epilogue: lane holds O^T[d = n*16+quad*4+r][q = m]; packed 8B stores
    #pragma unroll
    for (int g = 0; g < 2; g++) {
        const float inv = 1.f / l_run[g];
        __bf16* orow = gao + ((size_t)bh * S + q0 + g * 16 + m) * 64;
        #pragma unroll
        for (int n = 0; n < 4; n++) {
            *(unsigned long long*)(orow + n * 16 + quad * 4) =
                pack4bf(o[g][n][0] * inv, o[g][n][1] * inv,
                        o[g][n][2] * inv, o[g][n][3] * inv);
        }
    }
}

// ---------------------------------------------------------------------------
// Kernel 3: output projection, transposed (A=Wo) -> float4 stores.
// 128 rows/block.
// ---------------------------------------------------------------------------
__global__ __launch_bounds__(256) void out_proj(
    const __bf16* __restrict__ gao, const float* __restrict__ Wo,
    const float* __restrict__ bo, float* __restrict__ out)
{
    __shared__ __align__(16) __bf16 lx[128][LDS_PAD];
    __shared__ __align__(16) __bf16 lw[64][LDS_PAD];
    __shared__ float lb[64];

    const int tid = threadIdx.x;
    const int row_base = blockIdx.x * 128;

    #pragma unroll
    for (int i = tid; i < 1024; i += 256) {
        int r = i >> 3, c = (i & 7) * 8;
        *(uint4*)&lx[r][c] = *(const uint4*)(gao + (size_t)row_base * 64 + r * 64 + c);
    }
    #pragma unroll
    for (int i = tid * 4; i < 4096; i += 1024) {
        float4 v = *(const float4*)(Wo + i);
        int r = i >> 6, c = i & 63;
        *(unsigned long long*)&lw[r][c] = pack4bf(v.x, v.y, v.z, v.w);
    }
    if (tid < 64) lb[tid] = bo[tid];
    __syncthreads();

    const int w = tid >> 6, lane = tid & 63, m = lane & 15, quad = lane >> 4;
    bf16x8 xf[2][2];
    #pragma unroll
    for (int g = 0; g < 2; g++) {
        xf[g][0] = *(const bf16x8*)&lx[w * 32 + g * 16 + m][quad * 8];
        xf[g][1] = *(const bf16x8*)&lx[w * 32 + g * 16 + m][32 + quad * 8];
    }

    #pragma unroll
    for (int et = 0; et < 4; et++) {
        bf16x8 wf0 = *(const bf16x8*)&lw[et * 16 + m][quad * 8];
        bf16x8 wf1 = *(const bf16x8*)&lw[et * 16 + m][32 + quad * 8];
        float4 bias = *(const float4*)&lb[et * 16 + quad * 4];
        #pragma unroll
        for (int g = 0; g < 2; g++) {
            f32x4 acc = {0.f, 0.f, 0.f, 0.f};
            acc = MFMA(wf0, xf[g][0], acc);
            acc = MFMA(wf1, xf[g][1], acc);
            float4 res;
            res.x = acc[0] + bias.x; res.y = acc[1] + bias.y;
            res.z = acc[2] + bias.z; res.w = acc[3] + bias.w;
            size_t row = (size_t)row_base + w * 32 + g * 16 + m;
            *(float4*)(out + row * 64 + et * 16 + quad * 4) = res;
        }
    }
}

// ---------------------------------------------------------------------------
extern "C" void kernel_launch(void* const* d_in, const int* in_sizes, int n_in,
                              void* d_out, int out_size, void* d_ws, size_t ws_size,
                              hipStream_t stream) {
    const float* x  = (const float*)d_in[0];
    const float* Wq = (const float*)d_in[1];
    const float* bq = (const float*)d_in[2];
    const float* Wk = (const float*)d_in[3];
    const float* bk = (const float*)d_in[4];
    const float* Wv = (const float*)d_in[5];
    const float* bv = (const float*)d_in[6];
    const float* Wo = (const float*)d_in[7];
    const float* bo = (const float*)d_in[8];
    float* out = (float*)d_out;

    __bf16* gq  = (__bf16*)d_ws;
    __bf16* gk  = gq + NE;
    __bf16* gvt = gk + NE;
    __bf16* gao = gvt + NE;

    proj_qkv<<<1536, 256, 0, stream>>>(x, Wq, bq, Wk, bk, Wv, bv, gq, gk, gvt);
    attn<<<dim3(8, 192), 256, 0, stream>>>(gq, gk, gvt, gao);
    out_proj<<<1536, 256, 0, stream>>>(gao, Wo, bo, out);
}

// Round 3
// 230.086 us; speedup vs baseline: 1.3186x; 1.0533x over previous
//
#include <hip/hip_runtime.h>
#include <math.h>

// B=16, H=12, S=1024, D=64.  BH=192, rows = B*H*S = 196608.
// ws layout (bf16): Q[196608*64] | K[196608*64] | Vt[192*64*1024] | AO[196608*64]

typedef __bf16 bf16x8 __attribute__((ext_vector_type(8)));
typedef float  f32x4  __attribute__((ext_vector_type(4)));

#define MFMA(a, b, c) __builtin_amdgcn_mfma_f32_16x16x32_bf16((a), (b), (c), 0, 0, 0)

static constexpr int S = 1024;
static constexpr int LDS_PAD = 72;   // 144 B row stride: 16B-aligned, breaks 128B bank aliasing
static constexpr size_t NE = 196608ull * 64ull;
// Q prescale: 1/sqrt(64) * log2(e)  -> scores arrive pre-scaled for exp2
static constexpr float QSCALE = 0.125f * 1.4426950408889634f;

__device__ inline unsigned long long pack4bf(float a, float b, float c, float d) {
    union { __bf16 h[4]; unsigned long long u; } pk;
    pk.h[0] = (__bf16)a; pk.h[1] = (__bf16)b; pk.h[2] = (__bf16)c; pk.h[3] = (__bf16)d;
    return pk.u;
}

// ---------------------------------------------------------------------------
// Kernel 1: Q/K/V projection.  Block = 256 thr (4 waves), 128 rows/block.
// Q,K computed transposed (A=W) -> packed 8B stores; V computed direct (A=x)
// so Vt[bh][d][s] gets packed 8B stores along s.
// Q pre-scaled by QSCALE (1/sqrt(D) * log2e folded for exp2 softmax).
// ---------------------------------------------------------------------------
__global__ __launch_bounds__(256) void proj_qkv(
    const float* __restrict__ x,
    const float* __restrict__ Wq, const float* __restrict__ bq,
    const float* __restrict__ Wk, const float* __restrict__ bk,
    const float* __restrict__ Wv, const float* __restrict__ bv,
    __bf16* __restrict__ gq, __bf16* __restrict__ gk, __bf16* __restrict__ gvt)
{
    __shared__ __align__(16) __bf16 lx[128][LDS_PAD];
    __shared__ __align__(16) __bf16 lw[3][64][LDS_PAD];
    __shared__ float lb[3][64];

    const int tid = threadIdx.x;
    const int row_base = blockIdx.x * 128;

    #pragma unroll
    for (int i = tid * 4; i < 8192; i += 1024) {
        float4 v = *(const float4*)(x + (size_t)row_base * 64 + i);
        int r = i >> 6, c = i & 63;
        *(unsigned long long*)&lx[r][c] = pack4bf(v.x, v.y, v.z, v.w);
    }
    const float* Ws[3] = {Wq, Wk, Wv};
    #pragma unroll
    for (int mtx = 0; mtx < 3; mtx++) {
        #pragma unroll
        for (int i = tid * 4; i < 4096; i += 1024) {
            float4 v = *(const float4*)(Ws[mtx] + i);
            int r = i >> 6, c = i & 63;
            *(unsigned long long*)&lw[mtx][r][c] = pack4bf(v.x, v.y, v.z, v.w);
        }
    }
    if (tid < 64) { lb[0][tid] = bq[tid]; lb[1][tid] = bk[tid]; lb[2][tid] = bv[tid]; }
    __syncthreads();

    const int w = tid >> 6, lane = tid & 63, m = lane & 15, quad = lane >> 4;
    const int bh = row_base >> 10;
    const int s_base = row_base & 1023;

    bf16x8 xf[2][2];
    #pragma unroll
    for (int g = 0; g < 2; g++) {
        xf[g][0] = *(const bf16x8*)&lx[w * 32 + g * 16 + m][quad * 8];
        xf[g][1] = *(const bf16x8*)&lx[w * 32 + g * 16 + m][32 + quad * 8];
    }

    #pragma unroll
    for (int mtx = 0; mtx < 3; mtx++) {
        #pragma unroll
        for (int et = 0; et < 4; et++) {
            bf16x8 wf0 = *(const bf16x8*)&lw[mtx][et * 16 + m][quad * 8];
            bf16x8 wf1 = *(const bf16x8*)&lw[mtx][et * 16 + m][32 + quad * 8];
            if (mtx < 2) {
                float4 bias = *(const float4*)&lb[mtx][et * 16 + quad * 4];
                #pragma unroll
                for (int g = 0; g < 2; g++) {
                    f32x4 acc = {0.f, 0.f, 0.f, 0.f};
                    acc = MFMA(wf0, xf[g][0], acc);
                    acc = MFMA(wf1, xf[g][1], acc);
                    size_t row = (size_t)row_base + w * 32 + g * 16 + m;
                    unsigned long long u;
                    if (mtx == 0)
                        u = pack4bf((acc[0] + bias.x) * QSCALE, (acc[1] + bias.y) * QSCALE,
                                    (acc[2] + bias.z) * QSCALE, (acc[3] + bias.w) * QSCALE);
                    else
                        u = pack4bf(acc[0] + bias.x, acc[1] + bias.y,
                                    acc[2] + bias.z, acc[3] + bias.w);
                    __bf16* dst = (mtx == 0 ? gq : gk);
                    *(unsigned long long*)(dst + row * 64 + et * 16 + quad * 4) = u;
                }
            } else {
                const int e = et * 16 + m;
                const float bias = lb[2][e];
                #pragma unroll
                for (int g = 0; g < 2; g++) {
                    f32x4 acc = {0.f, 0.f, 0.f, 0.f};
                    acc = MFMA(xf[g][0], wf0, acc);
                    acc = MFMA(xf[g][1], wf1, acc);
                    unsigned long long u = pack4bf(acc[0] + bias, acc[1] + bias,
                                                   acc[2] + bias, acc[3] + bias);
                    int sl = s_base + w * 32 + g * 16 + quad * 4;
                    *(unsigned long long*)(gvt + ((size_t)bh * 64 + e) * 1024 + sl) = u;
                }
            }
        }
    }
}

// ---------------------------------------------------------------------------
// Kernel 2: flash attention, transposed dataflow, no-max softmax.
// Block = 256 thr (4 waves), 128 q rows/block; each wave owns 32 q rows.
// S^T = K * Q^T (pre-scaled for exp2); p = exp2(s'); row-sum l accumulated
// by an extra all-ones MFMA n-tile on the idle MFMA pipe.
// Grid dim3(192, 8): same-bh blocks share linear-id%8 -> same XCD -> K/V L2 hit.
// ---------------------------------------------------------------------------
__global__ __launch_bounds__(256) void attn(
    const __bf16* __restrict__ gq, const __bf16* __restrict__ gk,
    const __bf16* __restrict__ gvt, __bf16* __restrict__ gao)
{
    __shared__ __align__(16) __bf16 lk[64][LDS_PAD];        // K tile [key][d]
    __shared__ __align__(16) __bf16 lv[80][LDS_PAD];        // Vt tile [d][key]; rows 64-79 = 1.0
    __shared__ __align__(16) __bf16 lpT[4][32][LDS_PAD];    // per-wave P^T roundtrip [q][key]

    const int tid = threadIdx.x;
    const int w = tid >> 6, lane = tid & 63, m = lane & 15, quad = lane >> 4;
    const int bh = blockIdx.x;
    const int q0 = blockIdx.y * 128 + w * 32;

    // ones rows for the l-sum MFMA trick (written once; before first barrier)
    if (tid < 128) {
        uint4 ones;
        ones.x = 0x3F803F80u; ones.y = 0x3F803F80u;
        ones.z = 0x3F803F80u; ones.w = 0x3F803F80u;
        *(uint4*)&lv[64 + (tid >> 3)][(tid & 7) * 8] = ones;
    }

    // Q frags (B-operand) for two 16-row sets
    bf16x8 qf[2][2];
    #pragma unroll
    for (int g = 0; g < 2; g++) {
        const __bf16* qrow = gq + ((size_t)bh * S + q0 + g * 16 + m) * 64;
        qf[g][0] = *(const bf16x8*)(qrow + quad * 8);
        qf[g][1] = *(const bf16x8*)(qrow + 32 + quad * 8);
    }

    // o[g][0..3] = O^T accumulators; o[g][4] = l (row-sum via ones tile)
    f32x4 o[2][5];
    #pragma unroll
    for (int g = 0; g < 2; g++)
        #pragma unroll
        for (int n = 0; n < 5; n++) o[g][n] = {0.f, 0.f, 0.f, 0.f};

    const int sr = tid >> 3;            // 0..31
    const int sc = (tid & 7) * 8;       // element col (16B chunk)
    const __bf16* kbase = gk + (size_t)bh * S * 64;
    const __bf16* vbase = gvt + (size_t)bh * 64 * 1024;

    uint4 kreg0 = *(const uint4*)(kbase + (size_t)sr * 64 + sc);
    uint4 kreg1 = *(const uint4*)(kbase + (size_t)(sr + 32) * 64 + sc);
    uint4 vreg0 = *(const uint4*)(vbase + (size_t)sr * 1024 + sc);
    uint4 vreg1 = *(const uint4*)(vbase + (size_t)(sr + 32) * 1024 + sc);

    for (int kb = 0; kb < 16; kb++) {
        __syncthreads();
        *(uint4*)&lk[sr][sc]      = kreg0;
        *(uint4*)&lk[sr + 32][sc] = kreg1;
        *(uint4*)&lv[sr][sc]      = vreg0;
        *(uint4*)&lv[sr + 32][sc] = vreg1;
        if (kb < 15) {
            const int nb = (kb + 1) * 64;
            kreg0 = *(const uint4*)(kbase + (size_t)(nb + sr) * 64 + sc);
            kreg1 = *(const uint4*)(kbase + (size_t)(nb + sr + 32) * 64 + sc);
            vreg0 = *(const uint4*)(vbase + (size_t)sr * 1024 + nb + sc);
            vreg1 = *(const uint4*)(vbase + (size_t)(sr + 32) * 1024 + nb + sc);
        }
        __syncthreads();

        // scores S^T -> exp2 -> pack -> per-wave LDS, fused per key-subtile
        #pragma unroll
        for (int t = 0; t < 4; t++) {
            bf16x8 ka0 = *(const bf16x8*)&lk[t * 16 + m][quad * 8];
            bf16x8 ka1 = *(const bf16x8*)&lk[t * 16 + m][32 + quad * 8];
            #pragma unroll
            for (int g = 0; g < 2; g++) {
                f32x4 acc = {0.f, 0.f, 0.f, 0.f};
                acc = MFMA(ka0, qf[g][0], acc);
                acc = MFMA(ka1, qf[g][1], acc);
                *(unsigned long long*)&lpT[w][g * 16 + m][t * 16 + quad * 4] =
                    pack4bf(__builtin_exp2f(acc[0]), __builtin_exp2f(acc[1]),
                            __builtin_exp2f(acc[2]), __builtin_exp2f(acc[3]));
            }
        }

        bf16x8 pb[2][2];
        #pragma unroll
        for (int g = 0; g < 2; g++) {
            pb[g][0] = *(const bf16x8*)&lpT[w][g * 16 + m][quad * 8];
            pb[g][1] = *(const bf16x8*)&lpT[w][g * 16 + m][32 + quad * 8];
        }
        // PV: O^T[d][q] += V^T[d][key] * P^T[key][q]; n=4 is the ones tile -> l
        #pragma unroll
        for (int n = 0; n < 5; n++) {
            bf16x8 va0 = *(const bf16x8*)&lv[n * 16 + m][quad * 8];
            bf16x8 va1 = *(const bf16x8*)&lv[n * 16 + m][32 + quad * 8];
            #pragma unroll
            for (int g = 0; g < 2; g++) {
                o[g][n] = MFMA(va0, pb[g][0], o[g][n]);
                o[g][n] = MFMA(va1, pb[g][1], o[g][n]);
            }
        }
    }

    // epilogue: l is replicated in o[g][4][*]; normalize and store
    #pragma unroll
    for (int g = 0; g < 2; g++) {
        const float inv = 1.f / o[g][4][0];
        __bf16* orow = gao + ((size_t)bh * S + q0 + g * 16 + m) * 64;
        #pragma unroll
        for (int n = 0; n < 4; n++) {
            *(unsigned long long*)(orow + n * 16 + quad * 4) =
                pack4bf(o[g][n][0] * inv, o[g][n][1] * inv,
                        o[g][n][2] * inv, o[g][n][3] * inv);
        }
    }
}

// ---------------------------------------------------------------------------
// Kernel 3: output projection, transposed (A=Wo) -> float4 stores.
// ---------------------------------------------------------------------------
__global__ __launch_bounds__(256) void out_proj(
    const __bf16* __restrict__ gao, const float* __restrict__ Wo,
    const float* __restrict__ bo, float* __restrict__ out)
{
    __shared__ __align__(16) __bf16 lx[128][LDS_PAD];
    __shared__ __align__(16) __bf16 lw[64][LDS_PAD];
    __shared__ float lb[64];

    const int tid = threadIdx.x;
    const int row_base = blockIdx.x * 128;

    #pragma unroll
    for (int i = tid; i < 1024; i += 256) {
        int r = i >> 3, c = (i & 7) * 8;
        *(uint4*)&lx[r][c] = *(const uint4*)(gao + (size_t)row_base * 64 + r * 64 + c);
    }
    #pragma unroll
    for (int i = tid * 4; i < 4096; i += 1024) {
        float4 v = *(const float4*)(Wo + i);
        int r = i >> 6, c = i & 63;
        *(unsigned long long*)&lw[r][c] = pack4bf(v.x, v.y, v.z, v.w);
    }
    if (tid < 64) lb[tid] = bo[tid];
    __syncthreads();

    const int w = tid >> 6, lane = tid & 63, m = lane & 15, quad = lane >> 4;
    bf16x8 xf[2][2];
    #pragma unroll
    for (int g = 0; g < 2; g++) {
        xf[g][0] = *(const bf16x8*)&lx[w * 32 + g * 16 + m][quad * 8];
        xf[g][1] = *(const bf16x8*)&lx[w * 32 + g * 16 + m][32 + quad * 8];
    }

    #pragma unroll
    for (int et = 0; et < 4; et++) {
        bf16x8 wf0 = *(const bf16x8*)&lw[et * 16 + m][quad * 8];
        bf16x8 wf1 = *(const bf16x8*)&lw[et * 16 + m][32 + quad * 8];
        float4 bias = *(const float4*)&lb[et * 16 + quad * 4];
        #pragma unroll
        for (int g = 0; g < 2; g++) {
            f32x4 acc = {0.f, 0.f, 0.f, 0.f};
            acc = MFMA(wf0, xf[g][0], acc);
            acc = MFMA(wf1, xf[g][1], acc);
            float4 res;
            res.x = acc[0] + bias.x; res.y = acc[1] + bias.y;
            res.z = acc[2] + bias.z; res.w = acc[3] + bias.w;
            size_t row = (size_t)row_base + w * 32 + g * 16 + m;
            *(float4*)(out + row * 64 + et * 16 + quad * 4) = res;
        }
    }
}

// ---------------------------------------------------------------------------
extern "C" void kernel_launch(void* const* d_in, const int* in_sizes, int n_in,
                              void* d_out, int out_size, void* d_ws, size_t ws_size,
                              hipStream_t stream) {
    const float* x  = (const float*)d_in[0];
    const float* Wq = (const float*)d_in[1];
    const float* bq = (const float*)d_in[2];
    const float* Wk = (const float*)d_in[3];
    const float* bk = (const float*)d_in[4];
    const float* Wv = (const float*)d_in[5];
    const float* bv = (const float*)d_in[6];
    const float* Wo = (const float*)d_in[7];
    const float* bo = (const float*)d_in[8];
    float* out = (float*)d_out;

    __bf16* gq  = (__bf16*)d_ws;
    __bf16* gk  = gq + NE;
    __bf16* gvt = gk + NE;
    __bf16* gao = gvt + NE;

    proj_qkv<<<1536, 256, 0, stream>>>(x, Wq, bq, Wk, bk, Wv, bv, gq, gk, gvt);
    attn<<<dim3(192, 8), 256, 0, stream>>>(gq, gk, gvt, gao);
    out_proj<<<1536, 256, 0, stream>>>(gao, Wo, bo, out);
}

// Round 4
// 227.476 us; speedup vs baseline: 1.3337x; 1.0115x over previous
//
#include <hip/hip_runtime.h>
#include <math.h>

// B=16, H=12, S=1024, D=64.  BH=192, rows = B*H*S = 196608.
// ws layout (bf16): Q[NE] | K[NE] | Vt[NE] | Wo_bf16[4096]

typedef __bf16 bf16x8 __attribute__((ext_vector_type(8)));
typedef float  f32x4  __attribute__((ext_vector_type(4)));

#define MFMA(a, b, c) __builtin_amdgcn_mfma_f32_16x16x32_bf16((a), (b), (c), 0, 0, 0)

static constexpr int S = 1024;
static constexpr int PAD = 72;      // 144 B row stride: 16B-aligned (b128-legal), breaks 128B aliasing
static constexpr size_t NE = 196608ull * 64ull;
// Q prescale: 1/sqrt(64) * log2(e)  -> scores arrive pre-scaled for exp2
static constexpr float QSCALE = 0.125f * 1.4426950408889634f;

__device__ inline unsigned long long pack4bf(float a, float b, float c, float d) {
    union { __bf16 h[4]; unsigned long long u; } pk;
    pk.h[0] = (__bf16)a; pk.h[1] = (__bf16)b; pk.h[2] = (__bf16)c; pk.h[3] = (__bf16)d;
    return pk.u;
}

// ---------------------------------------------------------------------------
// Kernel 0: Wo fp32 -> bf16 (consumed by attn's fused output projection)
// ---------------------------------------------------------------------------
__global__ void wo_conv(const float* __restrict__ Wo, __bf16* __restrict__ wob) {
    int i = (blockIdx.x * 256 + threadIdx.x) * 4;
    float4 v = *(const float4*)(Wo + i);
    *(unsigned long long*)(wob + i) = pack4bf(v.x, v.y, v.z, v.w);
}

// ---------------------------------------------------------------------------
// Kernel 1: Q/K/V projection, 128 rows/block, coalesced stores via LDS roundtrip.
// Q,K via transposed orientation (A=W, C^T[e][s]); V via direct (A=x, C[s][e]).
// All global stores are 16 B/lane fully-coalesced after the roundtrip.
// ---------------------------------------------------------------------------
__global__ __launch_bounds__(256) void proj_qkv(
    const float* __restrict__ x,
    const float* __restrict__ Wq, const float* __restrict__ bq,
    const float* __restrict__ Wk, const float* __restrict__ bk,
    const float* __restrict__ Wv, const float* __restrict__ bv,
    __bf16* __restrict__ gq, __bf16* __restrict__ gk, __bf16* __restrict__ gvt)
{
    __shared__ __align__(16) __bf16 lx[128][PAD];
    __shared__ __align__(16) __bf16 lw[3][64][PAD];
    __shared__ __align__(16) __bf16 lbuf[128][PAD];   // roundtrip; reused as [64][136] for Vt
    __shared__ float lb[3][64];

    const int tid = threadIdx.x;
    const int row_base = blockIdx.x * 128;

    #pragma unroll
    for (int i = tid * 4; i < 8192; i += 1024) {
        float4 v = *(const float4*)(x + (size_t)row_base * 64 + i);
        int r = i >> 6, c = i & 63;
        *(unsigned long long*)&lx[r][c] = pack4bf(v.x, v.y, v.z, v.w);
    }
    const float* Ws[3] = {Wq, Wk, Wv};
    #pragma unroll
    for (int mtx = 0; mtx < 3; mtx++) {
        #pragma unroll
        for (int i = tid * 4; i < 4096; i += 1024) {
            float4 v = *(const float4*)(Ws[mtx] + i);
            int r = i >> 6, c = i & 63;
            *(unsigned long long*)&lw[mtx][r][c] = pack4bf(v.x, v.y, v.z, v.w);
        }
    }
    if (tid < 64) { lb[0][tid] = bq[tid]; lb[1][tid] = bk[tid]; lb[2][tid] = bv[tid]; }
    __syncthreads();

    const int w = tid >> 6, lane = tid & 63, m = lane & 15, quad = lane >> 4;
    const int bh = row_base >> 10;
    const int s_base = row_base & 1023;

    bf16x8 xf[2][2];
    #pragma unroll
    for (int g = 0; g < 2; g++) {
        xf[g][0] = *(const bf16x8*)&lx[w * 32 + g * 16 + m][quad * 8];
        xf[g][1] = *(const bf16x8*)&lx[w * 32 + g * 16 + m][32 + quad * 8];
    }

    // ---- Q then K: transposed orientation, roundtrip, coalesced store ----
    #pragma unroll
    for (int mtx = 0; mtx < 2; mtx++) {
        #pragma unroll
        for (int et = 0; et < 4; et++) {
            bf16x8 wf0 = *(const bf16x8*)&lw[mtx][et * 16 + m][quad * 8];
            bf16x8 wf1 = *(const bf16x8*)&lw[mtx][et * 16 + m][32 + quad * 8];
            float4 bias = *(const float4*)&lb[mtx][et * 16 + quad * 4];
            #pragma unroll
            for (int g = 0; g < 2; g++) {
                f32x4 acc = {0.f, 0.f, 0.f, 0.f};
                acc = MFMA(wf0, xf[g][0], acc);
                acc = MFMA(wf1, xf[g][1], acc);
                unsigned long long u;
                if (mtx == 0)
                    u = pack4bf((acc[0] + bias.x) * QSCALE, (acc[1] + bias.y) * QSCALE,
                                (acc[2] + bias.z) * QSCALE, (acc[3] + bias.w) * QSCALE);
                else
                    u = pack4bf(acc[0] + bias.x, acc[1] + bias.y,
                                acc[2] + bias.z, acc[3] + bias.w);
                *(unsigned long long*)&lbuf[w * 32 + g * 16 + m][et * 16 + quad * 4] = u;
            }
        }
        __syncthreads();
        __bf16* dst = (mtx == 0 ? gq : gk);
        #pragma unroll
        for (int it = 0; it < 4; it++) {
            int idx = it * 256 + tid;            // 16B chunk index, 0..1023
            int row = idx >> 3, col = (idx & 7) * 8;
            *(uint4*)(dst + ((size_t)row_base + row) * 64 + col) = *(uint4*)&lbuf[row][col];
        }
        __syncthreads();
    }

    // ---- V: direct orientation -> lvt[e][s_local] -> coalesced Vt store ----
    __bf16 (*lvt)[136] = (__bf16(*)[136])&lbuf[0][0];
    #pragma unroll
    for (int et = 0; et < 4; et++) {
        bf16x8 wf0 = *(const bf16x8*)&lw[2][et * 16 + m][quad * 8];
        bf16x8 wf1 = *(const bf16x8*)&lw[2][et * 16 + m][32 + quad * 8];
        const float bias = lb[2][et * 16 + m];
        #pragma unroll
        for (int g = 0; g < 2; g++) {
            f32x4 acc = {0.f, 0.f, 0.f, 0.f};
            acc = MFMA(xf[g][0], wf0, acc);
            acc = MFMA(xf[g][1], wf1, acc);
            *(unsigned long long*)&lvt[et * 16 + m][w * 32 + g * 16 + quad * 4] =
                pack4bf(acc[0] + bias, acc[1] + bias, acc[2] + bias, acc[3] + bias);
        }
    }
    __syncthreads();
    #pragma unroll
    for (int it = 0; it < 4; it++) {
        int idx = it * 256 + tid;                // 16B chunk, 0..1023
        int row = idx >> 4, col = (idx & 15) * 8;
        *(uint4*)(gvt + ((size_t)bh * 64 + row) * 1024 + s_base + col) = *(uint4*)&lvt[row][col];
    }
}

// ---------------------------------------------------------------------------
// Kernel 2: flash attention + fused output projection.
// Block = 4 waves, 256 q rows (64/wave, g=0..3).  Grid (192 bh, 4 qb):
// same-bh blocks land on the same XCD (192 % 8 == 0).
// S^T = K*Q^T -> exp2 -> P^T roundtrip (per-wave lp) -> O^T = V^T*P^T.
// l = sum(p) via fp32 adds, quad-reduced once at the end.
// Epilogue: O -> lp as [q][d] bf16 -> fused @ Wo^T + bo -> fp32 out.
// ---------------------------------------------------------------------------
__global__ __launch_bounds__(256) void attn(
    const __bf16* __restrict__ gq, const __bf16* __restrict__ gk,
    const __bf16* __restrict__ gvt, const __bf16* __restrict__ wob,
    const float* __restrict__ bo, float* __restrict__ out)
{
    __shared__ __align__(16) __bf16 lk[64][PAD];        // K tile [key][d]
    __shared__ __align__(16) __bf16 lv[64][PAD];        // Vt tile [d][key]
    __shared__ __align__(16) __bf16 lp[4][64][PAD];     // per-wave roundtrip [q][key] / [q][d]

    const int tid = threadIdx.x;
    const int w = tid >> 6, lane = tid & 63, m = lane & 15, quad = lane >> 4;
    const int bh = blockIdx.x;
    const int q0 = blockIdx.y * 256 + w * 64;

    bf16x8 qf[4][2];
    #pragma unroll
    for (int g = 0; g < 4; g++) {
        const __bf16* qrow = gq + ((size_t)bh * S + q0 + g * 16 + m) * 64;
        qf[g][0] = *(const bf16x8*)(qrow + quad * 8);
        qf[g][1] = *(const bf16x8*)(qrow + 32 + quad * 8);
    }

    f32x4 o[4][4];
    float lsum[4] = {0.f, 0.f, 0.f, 0.f};
    #pragma unroll
    for (int g = 0; g < 4; g++)
        #pragma unroll
        for (int n = 0; n < 4; n++) o[g][n] = {0.f, 0.f, 0.f, 0.f};

    const int sr = tid >> 3;            // 0..31
    const int sc = (tid & 7) * 8;       // 16B chunk col
    const __bf16* kbase = gk + (size_t)bh * S * 64;
    const __bf16* vbase = gvt + (size_t)bh * 64 * 1024;

    uint4 kreg0 = *(const uint4*)(kbase + (size_t)sr * 64 + sc);
    uint4 kreg1 = *(const uint4*)(kbase + (size_t)(sr + 32) * 64 + sc);
    uint4 vreg0 = *(const uint4*)(vbase + (size_t)sr * 1024 + sc);
    uint4 vreg1 = *(const uint4*)(vbase + (size_t)(sr + 32) * 1024 + sc);

    for (int kb = 0; kb < 16; kb++) {
        __syncthreads();
        *(uint4*)&lk[sr][sc]      = kreg0;
        *(uint4*)&lk[sr + 32][sc] = kreg1;
        *(uint4*)&lv[sr][sc]      = vreg0;
        *(uint4*)&lv[sr + 32][sc] = vreg1;
        if (kb < 15) {
            const int nb = (kb + 1) * 64;
            kreg0 = *(const uint4*)(kbase + (size_t)(nb + sr) * 64 + sc);
            kreg1 = *(const uint4*)(kbase + (size_t)(nb + sr + 32) * 64 + sc);
            vreg0 = *(const uint4*)(vbase + (size_t)sr * 1024 + nb + sc);
            vreg1 = *(const uint4*)(vbase + (size_t)(sr + 32) * 1024 + nb + sc);
        }
        __syncthreads();

        // scores S^T -> exp2 -> lsum + packed P^T to per-wave LDS
        #pragma unroll
        for (int t = 0; t < 4; t++) {
            bf16x8 ka0 = *(const bf16x8*)&lk[t * 16 + m][quad * 8];
            bf16x8 ka1 = *(const bf16x8*)&lk[t * 16 + m][32 + quad * 8];
            #pragma unroll
            for (int g = 0; g < 4; g++) {
                f32x4 acc = {0.f, 0.f, 0.f, 0.f};
                acc = MFMA(ka0, qf[g][0], acc);
                acc = MFMA(ka1, qf[g][1], acc);
                float e0 = __builtin_exp2f(acc[0]), e1 = __builtin_exp2f(acc[1]);
                float e2 = __builtin_exp2f(acc[2]), e3 = __builtin_exp2f(acc[3]);
                lsum[g] += (e0 + e1) + (e2 + e3);
                *(unsigned long long*)&lp[w][g * 16 + m][t * 16 + quad * 4] =
                    pack4bf(e0, e1, e2, e3);
            }
        }

        bf16x8 pb[4][2];
        #pragma unroll
        for (int g = 0; g < 4; g++) {
            pb[g][0] = *(const bf16x8*)&lp[w][g * 16 + m][quad * 8];
            pb[g][1] = *(const bf16x8*)&lp[w][g * 16 + m][32 + quad * 8];
        }
        #pragma unroll
        for (int n = 0; n < 4; n++) {
            bf16x8 va0 = *(const bf16x8*)&lv[n * 16 + m][quad * 8];
            bf16x8 va1 = *(const bf16x8*)&lv[n * 16 + m][32 + quad * 8];
            #pragma unroll
            for (int g = 0; g < 4; g++) {
                o[g][n] = MFMA(va0, pb[g][0], o[g][n]);
                o[g][n] = MFMA(va1, pb[g][1], o[g][n]);
            }
        }
    }

    // l: quad-reduce (keys were split across quads); then normalize O -> lp [q][d]
    #pragma unroll
    for (int g = 0; g < 4; g++) {
        lsum[g] += __shfl_xor(lsum[g], 16);
        lsum[g] += __shfl_xor(lsum[g], 32);
        const float inv = 1.f / lsum[g];
        #pragma unroll
        for (int n = 0; n < 4; n++) {
            *(unsigned long long*)&lp[w][g * 16 + m][n * 16 + quad * 4] =
                pack4bf(o[g][n][0] * inv, o[g][n][1] * inv,
                        o[g][n][2] * inv, o[g][n][3] * inv);
        }
    }

    // fused output projection: out[s][e] = O[s][:] @ Wo^T + bo  (direct orientation)
    bf16x8 wf[4][2];
    #pragma unroll
    for (int et = 0; et < 4; et++) {
        wf[et][0] = *(const bf16x8*)(wob + (size_t)(et * 16 + m) * 64 + quad * 8);
        wf[et][1] = *(const bf16x8*)(wob + (size_t)(et * 16 + m) * 64 + 32 + quad * 8);
    }
    float biasr[4];
    #pragma unroll
    for (int et = 0; et < 4; et++) biasr[et] = bo[et * 16 + m];

    #pragma unroll
    for (int g = 0; g < 4; g++) {
        bf16x8 af0 = *(const bf16x8*)&lp[w][g * 16 + m][quad * 8];
        bf16x8 af1 = *(const bf16x8*)&lp[w][g * 16 + m][32 + quad * 8];
        #pragma unroll
        for (int et = 0; et < 4; et++) {
            f32x4 acc = {0.f, 0.f, 0.f, 0.f};
            acc = MFMA(af0, wf[et][0], acc);
            acc = MFMA(af1, wf[et][1], acc);
            #pragma unroll
            for (int r = 0; r < 4; r++) {
                size_t row = (size_t)bh * S + q0 + g * 16 + quad * 4 + r;
                out[row * 64 + et * 16 + m] = acc[r] + biasr[et];
            }
        }
    }
}

// ---------------------------------------------------------------------------
extern "C" void kernel_launch(void* const* d_in, const int* in_sizes, int n_in,
                              void* d_out, int out_size, void* d_ws, size_t ws_size,
                              hipStream_t stream) {
    const float* x  = (const float*)d_in[0];
    const float* Wq = (const float*)d_in[1];
    const float* bq = (const float*)d_in[2];
    const float* Wk = (const float*)d_in[3];
    const float* bk = (const float*)d_in[4];
    const float* Wv = (const float*)d_in[5];
    const float* bv = (const float*)d_in[6];
    const float* Wo = (const float*)d_in[7];
    const float* bo = (const float*)d_in[8];
    float* out = (float*)d_out;

    __bf16* gq  = (__bf16*)d_ws;
    __bf16* gk  = gq + NE;
    __bf16* gvt = gk + NE;
    __bf16* wob = gvt + NE;

    wo_conv<<<4, 256, 0, stream>>>(Wo, wob);
    proj_qkv<<<1536, 256, 0, stream>>>(x, Wq, bq, Wk, bk, Wv, bv, gq, gk, gvt);
    attn<<<dim3(192, 4), 256, 0, stream>>>(gq, gk, gvt, wob, bo, out);
}

// Round 5
// 213.728 us; speedup vs baseline: 1.4195x; 1.0643x over previous
//
#include <hip/hip_runtime.h>
#include <math.h>

// B=16, H=12, S=1024, D=64.  BH=192, rows = B*H*S = 196608.
// ws layout (bf16): Q[NE] | K[NE] | Vt[NE] | Wo_bf16[4096]

typedef __bf16 bf16x8 __attribute__((ext_vector_type(8)));
typedef float  f32x4  __attribute__((ext_vector_type(4)));

#define MFMA(a, b, c) __builtin_amdgcn_mfma_f32_16x16x32_bf16((a), (b), (c), 0, 0, 0)

static constexpr int S = 1024;
static constexpr int PAD = 72;      // 144 B row stride: 16B-aligned (b128-legal), breaks 128B aliasing
static constexpr size_t NE = 196608ull * 64ull;
// Q prescale: 1/sqrt(64) * log2(e)  -> scores arrive pre-scaled for exp2
static constexpr float QSCALE = 0.125f * 1.4426950408889634f;

__device__ inline unsigned long long pack4bf(float a, float b, float c, float d) {
    union { __bf16 h[4]; unsigned long long u; } pk;
    pk.h[0] = (__bf16)a; pk.h[1] = (__bf16)b; pk.h[2] = (__bf16)c; pk.h[3] = (__bf16)d;
    return pk.u;
}

// ---------------------------------------------------------------------------
// Kernel 0: Wo fp32 -> bf16 (consumed by attn's fused output projection)
// ---------------------------------------------------------------------------
__global__ void wo_conv(const float* __restrict__ Wo, __bf16* __restrict__ wob) {
    int i = (blockIdx.x * 256 + threadIdx.x) * 4;
    float4 v = *(const float4*)(Wo + i);
    *(unsigned long long*)(wob + i) = pack4bf(v.x, v.y, v.z, v.w);
}

// ---------------------------------------------------------------------------
// Kernel 1: Q/K/V projection, 128 rows/block, coalesced stores via LDS roundtrip.
// (measured ~10-15 us total with wo_conv — not the bottleneck; unchanged)
// ---------------------------------------------------------------------------
__global__ __launch_bounds__(256) void proj_qkv(
    const float* __restrict__ x,
    const float* __restrict__ Wq, const float* __restrict__ bq,
    const float* __restrict__ Wk, const float* __restrict__ bk,
    const float* __restrict__ Wv, const float* __restrict__ bv,
    __bf16* __restrict__ gq, __bf16* __restrict__ gk, __bf16* __restrict__ gvt)
{
    __shared__ __align__(16) __bf16 lx[128][PAD];
    __shared__ __align__(16) __bf16 lw[3][64][PAD];
    __shared__ __align__(16) __bf16 lbuf[128][PAD];   // roundtrip; reused as [64][136] for Vt
    __shared__ float lb[3][64];

    const int tid = threadIdx.x;
    const int row_base = blockIdx.x * 128;

    #pragma unroll
    for (int i = tid * 4; i < 8192; i += 1024) {
        float4 v = *(const float4*)(x + (size_t)row_base * 64 + i);
        int r = i >> 6, c = i & 63;
        *(unsigned long long*)&lx[r][c] = pack4bf(v.x, v.y, v.z, v.w);
    }
    const float* Ws[3] = {Wq, Wk, Wv};
    #pragma unroll
    for (int mtx = 0; mtx < 3; mtx++) {
        #pragma unroll
        for (int i = tid * 4; i < 4096; i += 1024) {
            float4 v = *(const float4*)(Ws[mtx] + i);
            int r = i >> 6, c = i & 63;
            *(unsigned long long*)&lw[mtx][r][c] = pack4bf(v.x, v.y, v.z, v.w);
        }
    }
    if (tid < 64) { lb[0][tid] = bq[tid]; lb[1][tid] = bk[tid]; lb[2][tid] = bv[tid]; }
    __syncthreads();

    const int w = tid >> 6, lane = tid & 63, m = lane & 15, quad = lane >> 4;
    const int bh = row_base >> 10;
    const int s_base = row_base & 1023;

    bf16x8 xf[2][2];
    #pragma unroll
    for (int g = 0; g < 2; g++) {
        xf[g][0] = *(const bf16x8*)&lx[w * 32 + g * 16 + m][quad * 8];
        xf[g][1] = *(const bf16x8*)&lx[w * 32 + g * 16 + m][32 + quad * 8];
    }

    #pragma unroll
    for (int mtx = 0; mtx < 2; mtx++) {
        #pragma unroll
        for (int et = 0; et < 4; et++) {
            bf16x8 wf0 = *(const bf16x8*)&lw[mtx][et * 16 + m][quad * 8];
            bf16x8 wf1 = *(const bf16x8*)&lw[mtx][et * 16 + m][32 + quad * 8];
            float4 bias = *(const float4*)&lb[mtx][et * 16 + quad * 4];
            #pragma unroll
            for (int g = 0; g < 2; g++) {
                f32x4 acc = {0.f, 0.f, 0.f, 0.f};
                acc = MFMA(wf0, xf[g][0], acc);
                acc = MFMA(wf1, xf[g][1], acc);
                unsigned long long u;
                if (mtx == 0)
                    u = pack4bf((acc[0] + bias.x) * QSCALE, (acc[1] + bias.y) * QSCALE,
                                (acc[2] + bias.z) * QSCALE, (acc[3] + bias.w) * QSCALE);
                else
                    u = pack4bf(acc[0] + bias.x, acc[1] + bias.y,
                                acc[2] + bias.z, acc[3] + bias.w);
                *(unsigned long long*)&lbuf[w * 32 + g * 16 + m][et * 16 + quad * 4] = u;
            }
        }
        __syncthreads();
        __bf16* dst = (mtx == 0 ? gq : gk);
        #pragma unroll
        for (int it = 0; it < 4; it++) {
            int idx = it * 256 + tid;
            int row = idx >> 3, col = (idx & 7) * 8;
            *(uint4*)(dst + ((size_t)row_base + row) * 64 + col) = *(uint4*)&lbuf[row][col];
        }
        __syncthreads();
    }

    __bf16 (*lvt)[136] = (__bf16(*)[136])&lbuf[0][0];
    #pragma unroll
    for (int et = 0; et < 4; et++) {
        bf16x8 wf0 = *(const bf16x8*)&lw[2][et * 16 + m][quad * 8];
        bf16x8 wf1 = *(const bf16x8*)&lw[2][et * 16 + m][32 + quad * 8];
        const float bias = lb[2][et * 16 + m];
        #pragma unroll
        for (int g = 0; g < 2; g++) {
            f32x4 acc = {0.f, 0.f, 0.f, 0.f};
            acc = MFMA(xf[g][0], wf0, acc);
            acc = MFMA(xf[g][1], wf1, acc);
            *(unsigned long long*)&lvt[et * 16 + m][w * 32 + g * 16 + quad * 4] =
                pack4bf(acc[0] + bias, acc[1] + bias, acc[2] + bias, acc[3] + bias);
        }
    }
    __syncthreads();
    #pragma unroll
    for (int it = 0; it < 4; it++) {
        int idx = it * 256 + tid;
        int row = idx >> 4, col = (idx & 15) * 8;
        *(uint4*)(gvt + ((size_t)bh * 64 + row) * 1024 + s_base + col) = *(uint4*)&lvt[row][col];
    }
}

// ---------------------------------------------------------------------------
// Kernel 2: flash attention + fused output projection.
// Block = 4 waves, 256 q rows (64/wave, g=0..3 processed in PAIRS).
// LDS = lk(9.2K)+lv(9.2K)+lp(18.4K) = 36.9 KB -> 4 blocks/CU capacity ->
// all 768 blocks resident in ONE dispatch round (fixes r4's 1.5-round tail).
// exp2 via raw v_exp_f32 (__builtin_amdgcn_exp2f) — no libm guard sequence.
// Grid (192 bh, 4 qb): same-bh blocks share XCD -> K/V L2-resident.
// ---------------------------------------------------------------------------
__global__ __launch_bounds__(256) void attn(
    const __bf16* __restrict__ gq, const __bf16* __restrict__ gk,
    const __bf16* __restrict__ gvt, const __bf16* __restrict__ wob,
    const float* __restrict__ bo, float* __restrict__ out)
{
    __shared__ __align__(16) __bf16 lk[64][PAD];        // K tile [key][d]
    __shared__ __align__(16) __bf16 lv[64][PAD];        // Vt tile [d][key]
    __shared__ __align__(16) __bf16 lp[4][32][PAD];     // per-wave roundtrip, one g-PAIR slice

    const int tid = threadIdx.x;
    const int w = tid >> 6, lane = tid & 63, m = lane & 15, quad = lane >> 4;
    const int bh = blockIdx.x;
    const int q0 = blockIdx.y * 256 + w * 64;

    bf16x8 qf[4][2];
    #pragma unroll
    for (int g = 0; g < 4; g++) {
        const __bf16* qrow = gq + ((size_t)bh * S + q0 + g * 16 + m) * 64;
        qf[g][0] = *(const bf16x8*)(qrow + quad * 8);
        qf[g][1] = *(const bf16x8*)(qrow + 32 + quad * 8);
    }

    f32x4 o[4][4];
    float lsum[4] = {0.f, 0.f, 0.f, 0.f};
    #pragma unroll
    for (int g = 0; g < 4; g++)
        #pragma unroll
        for (int n = 0; n < 4; n++) o[g][n] = {0.f, 0.f, 0.f, 0.f};

    const int sr = tid >> 3;            // 0..31
    const int sc = (tid & 7) * 8;       // 16B chunk col
    const __bf16* kbase = gk + (size_t)bh * S * 64;
    const __bf16* vbase = gvt + (size_t)bh * 64 * 1024;

    uint4 kreg0 = *(const uint4*)(kbase + (size_t)sr * 64 + sc);
    uint4 kreg1 = *(const uint4*)(kbase + (size_t)(sr + 32) * 64 + sc);
    uint4 vreg0 = *(const uint4*)(vbase + (size_t)sr * 1024 + sc);
    uint4 vreg1 = *(const uint4*)(vbase + (size_t)(sr + 32) * 1024 + sc);

    for (int kb = 0; kb < 16; kb++) {
        __syncthreads();
        *(uint4*)&lk[sr][sc]      = kreg0;
        *(uint4*)&lk[sr + 32][sc] = kreg1;
        *(uint4*)&lv[sr][sc]      = vreg0;
        *(uint4*)&lv[sr + 32][sc] = vreg1;
        if (kb < 15) {
            const int nb = (kb + 1) * 64;
            kreg0 = *(const uint4*)(kbase + (size_t)(nb + sr) * 64 + sc);
            kreg1 = *(const uint4*)(kbase + (size_t)(nb + sr + 32) * 64 + sc);
            vreg0 = *(const uint4*)(vbase + (size_t)sr * 1024 + nb + sc);
            vreg1 = *(const uint4*)(vbase + (size_t)(sr + 32) * 1024 + nb + sc);
        }
        __syncthreads();

        // process q rows in two pairs: g = 2*gp + gl, gl in {0,1}
        #pragma unroll
        for (int gp = 0; gp < 2; gp++) {
            // score S^T -> exp2 (raw v_exp_f32) -> lsum + packed P^T slice
            #pragma unroll
            for (int t = 0; t < 4; t++) {
                bf16x8 ka0 = *(const bf16x8*)&lk[t * 16 + m][quad * 8];
                bf16x8 ka1 = *(const bf16x8*)&lk[t * 16 + m][32 + quad * 8];
                #pragma unroll
                for (int gl = 0; gl < 2; gl++) {
                    const int g = gp * 2 + gl;
                    f32x4 acc = {0.f, 0.f, 0.f, 0.f};
                    acc = MFMA(ka0, qf[g][0], acc);
                    acc = MFMA(ka1, qf[g][1], acc);
                    float e0 = __builtin_amdgcn_exp2f(acc[0]);
                    float e1 = __builtin_amdgcn_exp2f(acc[1]);
                    float e2 = __builtin_amdgcn_exp2f(acc[2]);
                    float e3 = __builtin_amdgcn_exp2f(acc[3]);
                    lsum[g] += (e0 + e1) + (e2 + e3);
                    *(unsigned long long*)&lp[w][gl * 16 + m][t * 16 + quad * 4] =
                        pack4bf(e0, e1, e2, e3);
                }
            }
            bf16x8 pb[2][2];
            #pragma unroll
            for (int gl = 0; gl < 2; gl++) {
                pb[gl][0] = *(const bf16x8*)&lp[w][gl * 16 + m][quad * 8];
                pb[gl][1] = *(const bf16x8*)&lp[w][gl * 16 + m][32 + quad * 8];
            }
            #pragma unroll
            for (int n = 0; n < 4; n++) {
                bf16x8 va0 = *(const bf16x8*)&lv[n * 16 + m][quad * 8];
                bf16x8 va1 = *(const bf16x8*)&lv[n * 16 + m][32 + quad * 8];
                #pragma unroll
                for (int gl = 0; gl < 2; gl++) {
                    const int g = gp * 2 + gl;
                    o[g][n] = MFMA(va0, pb[gl][0], o[g][n]);
                    o[g][n] = MFMA(va1, pb[gl][1], o[g][n]);
                }
            }
        }
    }

    // ---- fused output projection epilogue (per g-pair via lp; wave-private) ----
    bf16x8 wf[4][2];
    #pragma unroll
    for (int et = 0; et < 4; et++) {
        wf[et][0] = *(const bf16x8*)(wob + (size_t)(et * 16 + m) * 64 + quad * 8);
        wf[et][1] = *(const bf16x8*)(wob + (size_t)(et * 16 + m) * 64 + 32 + quad * 8);
    }
    float biasr[4];
    #pragma unroll
    for (int et = 0; et < 4; et++) biasr[et] = bo[et * 16 + m];

    #pragma unroll
    for (int g = 0; g < 4; g++) {
        lsum[g] += __shfl_xor(lsum[g], 16);
        lsum[g] += __shfl_xor(lsum[g], 32);
    }

    #pragma unroll
    for (int gp = 0; gp < 2; gp++) {
        // normalize O^T -> lp slice as [q][d]
        #pragma unroll
        for (int gl = 0; gl < 2; gl++) {
            const int g = gp * 2 + gl;
            const float inv = 1.f / lsum[g];
            #pragma unroll
            for (int n = 0; n < 4; n++) {
                *(unsigned long long*)&lp[w][gl * 16 + m][n * 16 + quad * 4] =
                    pack4bf(o[g][n][0] * inv, o[g][n][1] * inv,
                            o[g][n][2] * inv, o[g][n][3] * inv);
            }
        }
        // out[s][e] = O[s][:] @ Wo^T + bo
        #pragma unroll
        for (int gl = 0; gl < 2; gl++) {
            const int g = gp * 2 + gl;
            bf16x8 af0 = *(const bf16x8*)&lp[w][gl * 16 + m][quad * 8];
            bf16x8 af1 = *(const bf16x8*)&lp[w][gl * 16 + m][32 + quad * 8];
            #pragma unroll
            for (int et = 0; et < 4; et++) {
                f32x4 acc = {0.f, 0.f, 0.f, 0.f};
                acc = MFMA(af0, wf[et][0], acc);
                acc = MFMA(af1, wf[et][1], acc);
                #pragma unroll
                for (int r = 0; r < 4; r++) {
                    size_t row = (size_t)bh * S + q0 + g * 16 + quad * 4 + r;
                    out[row * 64 + et * 16 + m] = acc[r] + biasr[et];
                }
            }
        }
    }
}

// ---------------------------------------------------------------------------
extern "C" void kernel_launch(void* const* d_in, const int* in_sizes, int n_in,
                              void* d_out, int out_size, void* d_ws, size_t ws_size,
                              hipStream_t stream) {
    const float* x  = (const float*)d_in[0];
    const float* Wq = (const float*)d_in[1];
    const float* bq = (const float*)d_in[2];
    const float* Wk = (const float*)d_in[3];
    const float* bk = (const float*)d_in[4];
    const float* Wv = (const float*)d_in[5];
    const float* bv = (const float*)d_in[6];
    const float* Wo = (const float*)d_in[7];
    const float* bo = (const float*)d_in[8];
    float* out = (float*)d_out;

    __bf16* gq  = (__bf16*)d_ws;
    __bf16* gk  = gq + NE;
    __bf16* gvt = gk + NE;
    __bf16* wob = gvt + NE;

    wo_conv<<<4, 256, 0, stream>>>(Wo, wob);
    proj_qkv<<<1536, 256, 0, stream>>>(x, Wq, bq, Wk, bk, Wv, bv, gq, gk, gvt);
    attn<<<dim3(192, 4), 256, 0, stream>>>(gq, gk, gvt, wob, bo, out);
}